// Round 1
// baseline (473.808 us; speedup 1.0000x reference)
//
#include <hip/hip_runtime.h>

typedef _Float16 half_t;
typedef __attribute__((ext_vector_type(8))) _Float16 f16x8;
typedef __attribute__((ext_vector_type(4))) float f32x4;

#define DM 256
#define NH 8
#define HD 32
#define NN 256
#define NB 2
#define JT 128
#define KC 64

// ---------------- LayerNorm (one row per block, 256 threads) ----------------
__global__ __launch_bounds__(256) void k_ln(const float* __restrict__ in,
                                            const float* __restrict__ g,
                                            const float* __restrict__ be,
                                            float* __restrict__ out) {
  int row = blockIdx.x, t = threadIdx.x;
  float v = in[(size_t)row * DM + t];
  float s = v, q = v * v;
#pragma unroll
  for (int m = 1; m <= 32; m <<= 1) {
    s += __shfl_xor(s, m, 64);
    q += __shfl_xor(q, m, 64);
  }
  __shared__ float as_[4], aq_[4];
  int w = t >> 6, l = t & 63;
  if (l == 0) { as_[w] = s; aq_[w] = q; }
  __syncthreads();
  s = as_[0] + as_[1] + as_[2] + as_[3];
  q = aq_[0] + aq_[1] + aq_[2] + aq_[3];
  float mu = s * (1.0f / DM);
  float var = q * (1.0f / DM) - mu * mu;
  out[(size_t)row * DM + t] = (v - mu) * rsqrtf(var + 1e-5f) * g[t] + be[t];
}

// ---------------- W^T in f16 (for edge-proj MFMA B operand) ----------------
__global__ __launch_bounds__(256) void k_wt16(const float* __restrict__ W,
                                              half_t* __restrict__ WT) {
  int c = blockIdx.x, t = threadIdx.x;
  WT[c * DM + t] = (half_t)W[t * DM + c];
}

// ---------------- node projection: nqv = xs@W + b ; NQB = nqv + b ----------
__global__ __launch_bounds__(256) void k_proj_nodes(const float* __restrict__ xs,
                                                    const float* __restrict__ W,
                                                    const float* __restrict__ bias,
                                                    float* __restrict__ nqv,
                                                    float* __restrict__ NQB) {
  __shared__ float sx[8][DM];
  int t = threadIdx.x, r0 = blockIdx.x * 8;
#pragma unroll
  for (int r = 0; r < 8; ++r) sx[r][t] = xs[(size_t)(r0 + r) * DM + t];
  __syncthreads();
  float acc[8] = {0, 0, 0, 0, 0, 0, 0, 0};
  for (int k = 0; k < DM; ++k) {
    float wv = W[k * DM + t];
#pragma unroll
    for (int r = 0; r < 8; ++r) acc[r] += sx[r][k] * wv;
  }
  float bb = bias[t];
#pragma unroll
  for (int r = 0; r < 8; ++r) {
    float nv = acc[r] + bb;
    nqv[(size_t)(r0 + r) * DM + t] = nv;
    NQB[(size_t)(r0 + r) * DM + t] = nv + bb;  // eq bias folded in
  }
}

// ---------------- fused edge projection + scores ---------------------------
// grid 1024: (b, i, jb). Per block: E = edges[b,i,j0:j0+128,:] @ W  (f16 MFMA,
// f32 accum, E kept in registers), then per-head scores with tanh clip.
__global__ __launch_bounds__(256, 1) void k_edge_scores(
    const float* __restrict__ edges, const half_t* __restrict__ WT,
    const float* __restrict__ NQB, float* __restrict__ scores) {
  __shared__ __align__(16) char smem[65536];
  const int tid = threadIdx.x;
  const int l = tid & 63;
  const int w = tid >> 6;
  const int r0 = (w & 1) * 64;
  const int c0 = (w >> 1) * 128;
  const int idx = blockIdx.x;
  const int jb = idx & 1;
  const int i = (idx >> 1) & (NN - 1);
  const int b = idx >> 9;
  const int j0 = jb * JT;

  f32x4 acc[4][8];
#pragma unroll
  for (int mt = 0; mt < 4; ++mt)
#pragma unroll
    for (int nt = 0; nt < 8; ++nt) acc[mt][nt] = (f32x4){0.f, 0.f, 0.f, 0.f};

  const float* eg = edges + ((size_t)(b * NN + i) * NN + j0) * DM;
  const uint4* wt4 = (const uint4*)WT;

  for (int kc = 0; kc < 4; ++kc) {
    // stage A chunk: 128 rows x 64 k, f32 -> f16, XOR-swizzled
#pragma unroll
    for (int p = 0; p < 8; ++p) {
      int flat = p * 256 + tid;  // 2048 float4 units
      int row = flat >> 4, f4 = flat & 15;
      float4 v = *(const float4*)(eg + row * DM + kc * KC + f4 * 4);
      union { uint2 u; half_t h[4]; } pk;
      pk.h[0] = (half_t)v.x; pk.h[1] = (half_t)v.y;
      pk.h[2] = (half_t)v.z; pk.h[3] = (half_t)v.w;
      int off = (row * 128 + f4 * 8) ^ ((row & 7) << 4);
      *(uint2*)(smem + off) = pk.u;
    }
    // stage W^T chunk: 256 cols x 64 k (f16), XOR-swizzled
#pragma unroll
    for (int p = 0; p < 8; ++p) {
      int unit = p * 256 + tid;  // 2048 16B units
      int c = unit >> 3, k8 = unit & 7;
      uint4 v = wt4[c * 32 + kc * 8 + k8];
      int off = (16384 + c * 128 + k8 * 16) ^ ((c & 7) << 4);
      *(uint4*)(smem + off) = v;
    }
    __syncthreads();
#pragma unroll
    for (int sub = 0; sub < 2; ++sub) {
      f16x8 af[4];
#pragma unroll
      for (int mt = 0; mt < 4; ++mt) {
        int row = r0 + mt * 16 + (l & 15);
        int off = (row * 128 + sub * 64 + ((l >> 4) * 16)) ^ ((row & 7) << 4);
        af[mt] = *(const f16x8*)(smem + off);
      }
      f16x8 bf[8];
#pragma unroll
      for (int nt = 0; nt < 8; ++nt) {
        int c = c0 + nt * 16 + (l & 15);
        int off = (16384 + c * 128 + sub * 64 + ((l >> 4) * 16)) ^ ((c & 7) << 4);
        bf[nt] = *(const f16x8*)(smem + off);
      }
#pragma unroll
      for (int mt = 0; mt < 4; ++mt)
#pragma unroll
        for (int nt = 0; nt < 8; ++nt)
          acc[mt][nt] = __builtin_amdgcn_mfma_f32_16x16x32_f16(af[mt], bf[nt],
                                                               acc[mt][nt], 0, 0, 0);
    }
    __syncthreads();
  }

  // restage NQB[b, j0:j0+128, :] as f16 into LDS for q_j reads
  const float* nqb_blk = NQB + ((size_t)(b * NN) + j0) * DM;
#pragma unroll
  for (int p = 0; p < 32; ++p) {
    int flat = p * 256 + tid;  // 8192 float4 units
    int row = flat >> 6, c4 = flat & 63;
    float4 v = *(const float4*)(nqb_blk + row * DM + c4 * 4);
    union { uint2 u; half_t h[4]; } pk;
    pk.h[0] = (half_t)v.x; pk.h[1] = (half_t)v.y;
    pk.h[2] = (half_t)v.z; pk.h[3] = (half_t)v.w;
    *(uint2*)(smem + row * 512 + c4 * 8) = pk.u;
  }
  __syncthreads();

  float qi[8];
#pragma unroll
  for (int nt = 0; nt < 8; ++nt)
    qi[nt] = NQB[((size_t)(b * NN) + i) * DM + c0 + nt * 16 + (l & 15)];

  const float scale = 0.17677669529663687f;  // 1/sqrt(32)
#pragma unroll
  for (int mt = 0; mt < 4; ++mt) {
#pragma unroll
    for (int rr = 0; rr < 4; ++rr) {
      int row_l = r0 + mt * 16 + (l >> 4) * 4 + rr;
      float shv[4] = {0.f, 0.f, 0.f, 0.f};
#pragma unroll
      for (int nt = 0; nt < 8; ++nt) {
        float e = acc[mt][nt][rr];
        float qj = (float)*(const half_t*)(smem + row_l * 512 +
                                           (c0 + nt * 16 + (l & 15)) * 2);
        float u = (e + qi[nt]) * (e + qj);
        shv[nt >> 1] += u;  // unrolled -> static index
      }
#pragma unroll
      for (int hh = 0; hh < 4; ++hh) {
        float s = shv[hh];
        s += __shfl_xor(s, 1, 64);
        s += __shfl_xor(s, 2, 64);
        s += __shfl_xor(s, 4, 64);
        s += __shfl_xor(s, 8, 64);
        if ((l & 15) == 0) {
          int head = (c0 >> 5) + hh;
          int jg = j0 + row_l;
          scores[(((size_t)(b * NH) + head) * NN + i) * NN + jg] =
              10.0f * tanhf(s * scale);
        }
      }
    }
  }
}

// ---------------- softmax over j (one row per wave) ------------------------
__global__ __launch_bounds__(256) void k_softmax(float* __restrict__ sc) {
  int w = threadIdx.x >> 6, l = threadIdx.x & 63;
  size_t row = (size_t)blockIdx.x * 4 + w;
  float4 v = *(float4*)(sc + row * NN + l * 4);
  float m = fmaxf(fmaxf(v.x, v.y), fmaxf(v.z, v.w));
#pragma unroll
  for (int mm = 1; mm <= 32; mm <<= 1) m = fmaxf(m, __shfl_xor(m, mm, 64));
  v.x = __expf(v.x - m); v.y = __expf(v.y - m);
  v.z = __expf(v.z - m); v.w = __expf(v.w - m);
  float s = v.x + v.y + v.z + v.w;
#pragma unroll
  for (int mm = 1; mm <= 32; mm <<= 1) s += __shfl_xor(s, mm, 64);
  float inv = 1.0f / s;
  v.x *= inv; v.y *= inv; v.z *= inv; v.w *= inv;
  *(float4*)(sc + row * NN + l * 4) = v;
}

// ---------------- attn @ V  (block per (b,i)) ------------------------------
__global__ __launch_bounds__(256) void k_av(const float* __restrict__ attn,
                                            const float* __restrict__ nqv,
                                            float* __restrict__ ao) {
  __shared__ float sp[NH * NN];
  int t = threadIdx.x;
  int b = blockIdx.x >> 8, i = blockIdx.x & 255;
#pragma unroll
  for (int p = 0; p < 8; ++p) {
    int idx = p * 256 + t;
    int h = idx >> 8, j = idx & 255;
    sp[idx] = attn[(((size_t)(b * NH) + h) * NN + i) * NN + j];
  }
  __syncthreads();
  float acc = 0.f;
  int h = t >> 5;
  const float* vb = nqv + (size_t)b * NN * DM;
  for (int j = 0; j < NN; ++j) acc += sp[h * 256 + j] * vb[j * DM + t];
  ao[((size_t)(b * NN) + i) * DM + t] = acc;
}

// ---------------- out proj + residual --------------------------------------
__global__ __launch_bounds__(256) void k_projres(const float* __restrict__ ao,
                                                 const float* __restrict__ W,
                                                 const float* __restrict__ bias,
                                                 const float* __restrict__ xs,
                                                 float* __restrict__ ysr) {
  __shared__ float sa[8][DM];
  int t = threadIdx.x, r0 = blockIdx.x * 8;
#pragma unroll
  for (int r = 0; r < 8; ++r) sa[r][t] = ao[(size_t)(r0 + r) * DM + t];
  __syncthreads();
  float acc[8] = {0, 0, 0, 0, 0, 0, 0, 0};
  for (int k = 0; k < DM; ++k) {
    float wv = W[k * DM + t];
#pragma unroll
    for (int r = 0; r < 8; ++r) acc[r] += sa[r][k] * wv;
  }
  float bb = bias[t];
#pragma unroll
  for (int r = 0; r < 8; ++r)
    ysr[(size_t)(r0 + r) * DM + t] = xs[(size_t)(r0 + r) * DM + t] + acc[r] + bb;
}

// ---------------- feed-forward (exact GELU) + residual ---------------------
__global__ __launch_bounds__(256) void k_ffn(const float* __restrict__ ys,
                                             const float* __restrict__ W1,
                                             const float* __restrict__ b1,
                                             const float* __restrict__ W2,
                                             const float* __restrict__ b2,
                                             float* __restrict__ out) {
  __shared__ float sy[4][DM];
  __shared__ float sg[4][4 * DM];
  int t = threadIdx.x, r0 = blockIdx.x * 4;
#pragma unroll
  for (int r = 0; r < 4; ++r) sy[r][t] = ys[(size_t)(r0 + r) * DM + t];
  __syncthreads();
#pragma unroll
  for (int mc = 0; mc < 4; ++mc) {
    int m = mc * 256 + t;
    float acc[4];
    float bb = b1[m];
#pragma unroll
    for (int r = 0; r < 4; ++r) acc[r] = bb;
    for (int k = 0; k < DM; ++k) {
      float wv = W1[k * 1024 + m];
#pragma unroll
      for (int r = 0; r < 4; ++r) acc[r] += sy[r][k] * wv;
    }
#pragma unroll
    for (int r = 0; r < 4; ++r) {
      float v = acc[r];
      sg[r][m] = 0.5f * v * (1.0f + erff(v * 0.70710678118654752f));
    }
  }
  __syncthreads();
  float z[4];
  float bb2 = b2[t];
#pragma unroll
  for (int r = 0; r < 4; ++r) z[r] = bb2 + sy[r][t];
  for (int m = 0; m < 1024; ++m) {
    float wv = W2[m * 256 + t];
#pragma unroll
    for (int r = 0; r < 4; ++r) z[r] += sg[r][m] * wv;
  }
#pragma unroll
  for (int r = 0; r < 4; ++r) out[(size_t)(r0 + r) * DM + t] = z[r];
}

extern "C" void kernel_launch(void* const* d_in, const int* in_sizes, int n_in,
                              void* d_out, int out_size, void* d_ws, size_t ws_size,
                              hipStream_t stream) {
  const float* nodes = (const float*)d_in[0];
  const float* edges = (const float*)d_in[1];
  const float* W     = (const float*)d_in[2];
  const float* bias  = (const float*)d_in[3];
  const float* ln_g  = (const float*)d_in[4];
  const float* ln_b  = (const float*)d_in[5];
  const float* W1    = (const float*)d_in[6];
  const float* b1    = (const float*)d_in[7];
  const float* W2    = (const float*)d_in[8];
  const float* b2    = (const float*)d_in[9];
  float* out = (float*)d_out;

  char* ws = (char*)d_ws;
  float*  xs     = (float*)(ws + 0x000000);   // 512 KB
  float*  nqv    = (float*)(ws + 0x080000);   // 512 KB
  float*  NQB    = (float*)(ws + 0x100000);   // 512 KB
  half_t* WT16   = (half_t*)(ws + 0x180000);  // 128 KB
  float*  scores = (float*)(ws + 0x1A0000);   // 4 MB
  float*  ao     = (float*)(ws + 0x5A0000);   // 512 KB
  float*  ysr    = (float*)(ws + 0x620000);   // 512 KB
  float*  ys     = (float*)(ws + 0x6A0000);   // 512 KB

  k_ln<<<NB * NN, 256, 0, stream>>>(nodes, ln_g, ln_b, xs);
  k_wt16<<<DM, 256, 0, stream>>>(W, WT16);
  k_proj_nodes<<<NB * NN / 8, 256, 0, stream>>>(xs, W, bias, nqv, NQB);
  k_edge_scores<<<NB * NN * 2, 256, 0, stream>>>(edges, WT16, NQB, scores);
  k_softmax<<<NB * NH * NN / 4, 256, 0, stream>>>(scores);
  k_av<<<NB * NN, 256, 0, stream>>>(scores, nqv, ao);
  k_projres<<<NB * NN / 8, 256, 0, stream>>>(ao, W, bias, xs, ysr);
  k_ln<<<NB * NN, 256, 0, stream>>>(ysr, ln_g, ln_b, ys);
  k_ffn<<<NB * NN / 4, 256, 0, stream>>>(ys, W1, b1, W2, b2, out);
}